// Round 11
// baseline (127.306 us; speedup 1.0000x reference)
//
#include <hip/hip_runtime.h>

#define PCNT 128
#define RCdim 256
#define IMG (RCdim*RCdim)
#define PITCH_I 84        // interleaved row pitch (2 planes x 40 cols + 4 pad); %4==0 (b128 align), %32==20 (row spread)
#define TROWS 36
#define IELEMS (TROWS*PITCH_I)  // 3024 floats per interleaved plane
#define NSLOT 360
#define NTHREADS 256
#define NTHREADS_R 128

__device__ __forceinline__ float sig_(float x){ return 1.0f/(1.0f+__expf(-x)); }
__device__ __forceinline__ float th_(float x){ float e=__expf(2.0f*x); return 1.0f-2.0f/(e+1.0f); }

// fp32 -> bf16 RNE
__device__ __forceinline__ unsigned short f2bf(float f){
  unsigned u = __float_as_uint(f);
  u = (u + 0x7fffu + ((u >> 16) & 1u)) >> 16;
  return (unsigned short)u;
}
__device__ __forceinline__ void store_bf4(unsigned short* __restrict__ dst, const float v[4]){
  uint2 p;
  p.x = (unsigned)f2bf(v[0]) | ((unsigned)f2bf(v[1]) << 16);
  p.y = (unsigned)f2bf(v[2]) | ((unsigned)f2bf(v[3]) << 16);
  *(uint2*)dst = p;
}

// Interleaved pair layout: pair g = floats [4g,4g+4) = {A(2g-1), A(2g), B(2g-1), B(2g)}.
// f_A(c) = (c even) ? 2c+1 : 2c+2 ; f_B(c) = f_A(c)+2. Tile origin (R0-2, C0-4), cols 0..39.
__device__ __forceinline__ void stageP(const float* __restrict__ src, float* __restrict__ dst,
                                       int R0, int C0, int tid, int boff){
#pragma unroll
  for (int j=0;j<2;++j){
    int s = j*NTHREADS + tid;
    if (s < NSLOT){
      int rr = s/10, q = s - rr*10;
      int gr = R0-2+rr, gc = C0-4+4*q;
      float4 v = make_float4(0.f,0.f,0.f,0.f);
      if ((unsigned)gr < 256u && (unsigned)gc < 253u)
        v = *(const float4*)(src + gr*RCdim + gc);
      float* d = dst + rr*PITCH_I + 8*q + boff;
      d[1] = v.x;                                // col 4q   -> 8q+1
      *(float2*)(d+4) = make_float2(v.y, v.z);   // cols 4q+1,4q+2 -> 8q+4,8q+5
      d[8] = v.w;                                // col 4q+3 -> 8q+8
    }
  }
}
__device__ __forceinline__ void stageI(const float* __restrict__ P, float* __restrict__ dst,
                                       int R0, int C0, int tid){
  stageP(P,        dst, R0,C0,tid, 0);
  stageP(P + IMG,  dst, R0,C0,tid, 2);
}

// Window read: pairs g0..g0+2, rows row0..row0+2 -> WA/WB[3][6]; index i <-> col 2*g0-1+i
__device__ __forceinline__ void loadW(const float* __restrict__ T, int row0, int g0,
                                      float WA[3][6], float WB[3][6]){
#pragma unroll
  for (int dy=0;dy<3;++dy){
    const float4* p = (const float4*)&T[(row0+dy)*PITCH_I + 4*g0];
#pragma unroll
    for (int j=0;j<3;++j){
      float4 v = p[j];
      WA[dy][2*j]=v.x; WA[dy][2*j+1]=v.y; WB[dy][2*j]=v.z; WB[dy][2*j+1]=v.w;
    }
  }
}

// Paired 3x3 conv, 4 centers c0..c0+3 where c0 = 2*g0+1... (window col index k+kx)
__device__ __forceinline__ void convP(const float WA[3][6], const float WB[3][6],
                                      const float w0[9], const float w1[9], float o[4]){
#pragma unroll
  for (int ky=0;ky<3;++ky)
#pragma unroll
    for (int kx=0;kx<3;++kx){
      const float a = w0[ky*3+kx], b = w1[ky*3+kx];
#pragma unroll
      for (int k=0;k<4;++k){
        o[k] = fmaf(a, WA[ky][k+kx], o[k]);
        o[k] = fmaf(b, WB[ky][k+kx], o[k]);
      }
    }
}

// Single-px window: pairs g0, g0+1 -> SA/SB[3][4]; index i <-> col 2*g0-1+i
__device__ __forceinline__ void loadS(const float* __restrict__ T, int row0, int g0,
                                      float SA[3][4], float SB[3][4]){
#pragma unroll
  for (int dy=0;dy<3;++dy){
    const float4* p = (const float4*)&T[(row0+dy)*PITCH_I + 4*g0];
    float4 v = p[0], w = p[1];
    SA[dy][0]=v.x; SA[dy][1]=v.y; SA[dy][2]=w.x; SA[dy][3]=w.y;
    SB[dy][0]=v.z; SB[dy][1]=v.w; SB[dy][2]=w.z; SB[dy][3]=w.w;
  }
}
// single conv; center col c: window offset 0 (c even) or 1 (c odd); static index both paths
__device__ __forceinline__ float convS(const float SA[3][4], const float SB[3][4],
                                       const float w0[9], const float w1[9], float b, int odd){
  float r = b;
  if (odd){
#pragma unroll
    for (int ky=0;ky<3;++ky)
#pragma unroll
      for (int kx=0;kx<3;++kx){
        r = fmaf(w0[ky*3+kx], SA[ky][1+kx], r);
        r = fmaf(w1[ky*3+kx], SB[ky][1+kx], r);
      }
  } else {
#pragma unroll
    for (int ky=0;ky<3;++ky)
#pragma unroll
      for (int kx=0;kx<3;++kx){
        r = fmaf(w0[ky*3+kx], SA[ky][kx], r);
        r = fmaf(w1[ky*3+kx], SB[ky][kx], r);
      }
  }
  return r;
}

__device__ __forceinline__ void load_w18(const float* __restrict__ g, float w0[9], float w1[9]){
#pragma unroll
  for (int i=0;i<9;++i){ w0[i]=g[i]; w1[i]=g[9+i]; }
}

__global__ void init_out(const float* __restrict__ bias, float* __restrict__ out){
  int i = blockIdx.x * NTHREADS + threadIdx.x;
  out[i] = bias[i];
}

// out[px] = bias[px] + sum_p ns[p][px]*w_read[px][p]; ns bf16, 2 px/thread
__global__ void __launch_bounds__(NTHREADS_R)
reduce_out(const unsigned short* __restrict__ ns, const float* __restrict__ w_read,
           const float* __restrict__ bias, float* __restrict__ out){
  const int px0 = (blockIdx.x*NTHREADS_R + threadIdx.x)*2;
  float acc0 = bias[px0], acc1 = bias[px0+1];
  const float* wr0 = w_read + (size_t)px0*PCNT;
  const float* wr1 = wr0 + PCNT;
#pragma unroll 4
  for (int p0 = 0; p0 < PCNT; p0 += 4){
    const float4 wa = *(const float4*)&wr0[p0];
    const float4 wb = *(const float4*)&wr1[p0];
#pragma unroll
    for (int j=0;j<4;++j){
      unsigned v = *(const unsigned*)&ns[(size_t)(p0+j)*IMG + px0];
      float n0 = __uint_as_float(v << 16);
      float n1 = __uint_as_float(v & 0xffff0000u);
      acc0 = fmaf(n0, (&wa.x)[j], acc0);
      acc1 = fmaf(n1, (&wb.x)[j], acc1);
    }
  }
  out[px0]   = acc0;
  out[px0+1] = acc1;
}

// 3 interleaved LDS planes: I0 = (src_a0, src_a1) -> becomes (hr_a, hr_{a+1});
// I1 = (src_b0, src_b1); I2 = (h_a, h_{a+1}). All convs read plane-PAIRS as 9x b128.
// hr region rows 1..34, cols 3..36: interior = own strips; 84 edge tasks (tid<84).
template<bool SPLIT>
__global__ void __launch_bounds__(NTHREADS, 4)
gru_fused(const float* __restrict__ x, const float* __restrict__ h,
          const float* __restrict__ w_reset, const float* __restrict__ b_reset,
          const float* __restrict__ w_update, const float* __restrict__ b_update,
          const float* __restrict__ w_out, const float* __restrict__ b_out,
          const float* __restrict__ w_read, unsigned short* __restrict__ wsb,
          float* __restrict__ out)
{
  __shared__ float sm[3][IELEMS];  // 36288 B -> 4 blocks/CU
  const int tid  = threadIdx.x;
  const int bid  = blockIdx.x;
  const int pg   = bid & 15;
  const int tile = bid >> 4;
  const int R0 = (tile >> 3) * 32;
  const int C0 = (tile & 7) * 32;
  const int trow = tid >> 3;        // 0..31
  const int tcol = (tid & 7) * 4;   // 0..28
  const int gidx = (R0 + trow) * RCdim + C0 + tcol;
  const int gC   = (tcol + 4) >> 1; // strip window pair base (centers tcol+4..+7)

  // edge tasks: rows 1/34 (8 strips + 2 singles each), cols 3/36 rows 2..33 (64 singles)
  const bool eAct = tid < 84;
  int erow = 1, ec0 = 4; bool estrip = false;
  if (tid < 20){
    int u = tid % 10;
    erow = (tid < 10) ? 1 : 34;
    if (u < 8){ estrip = true; ec0 = 4 + 4*u; }
    else      { ec0 = (u == 8) ? 3 : 36; }
  } else if (eAct){
    erow = 2 + ((tid - 20) & 31);
    ec0  = (tid < 52) ? 3 : 36;
  }

  float acc[4] = {0.f,0.f,0.f,0.f};

#pragma unroll 1
  for (int it = 0; it < 4; ++it){
    const bool low = (it < 2);
    const int t = it & 1;
    int a, ph;
    const float *s0p, *s1p;
    if (low){
      a = 4*pg + 2*t; ph = 64 + 2*pg + t;
      s0p = x + (size_t)(2*a)*IMG;       // x_{2a}, x_{2a+1}
      s1p = x + (size_t)(2*a+2)*IMG;     // x_{2a+2}, x_{2a+3}
    } else {
      a = 64 + 4*pg + 2*t; ph = 96 + 2*pg + t;
      const int base = 8*pg + 4*t;
      s0p = h + (size_t)base*IMG;
      s1p = h + (size_t)(base+2)*IMG;
    }

    __syncthreads();   // protect LDS from previous iteration's readers
    stageI(s0p,                 sm[0], R0,C0,tid);
    stageI(s1p,                 sm[1], R0,C0,tid);
    stageI(h + (size_t)a*IMG,   sm[2], R0,C0,tid);
    __syncthreads();

    float upd[4], hc0[4], hc1[4];
    { // update conv for ph over I2 (h_a, h_{a+1}); capture centers
      float WA[3][6], WB[3][6], wt0[9], wt1[9];
      loadW(sm[2], trow+1, gC, WA, WB);
      load_w18(w_update + ph*18, wt0, wt1);
      const float bu = b_update[ph];
      upd[0]=bu; upd[1]=bu; upd[2]=bu; upd[3]=bu;
      convP(WA, WB, wt0, wt1, upd);
#pragma unroll
      for (int k=0;k<4;++k){ hc0[k]=WA[1][k+1]; hc1[k]=WB[1][k+1]; }
    }

    float ra[4];
    { // strip over I0: reset_a (+ low plant a gates)
      float WA[3][6], WB[3][6], wt0[9], wt1[9];
      loadW(sm[0], trow+1, gC, WA, WB);
      load_w18(w_reset + a*18, wt0, wt1);
      const float br = b_reset[a];
      ra[0]=br; ra[1]=br; ra[2]=br; ra[3]=br;
      convP(WA, WB, wt0, wt1, ra);
      if (low){
        load_w18(w_update + a*18, wt0, wt1);
        const float bu = b_update[a];
        float uo[4]={bu,bu,bu,bu};
        convP(WA, WB, wt0, wt1, uo);
        load_w18(w_out + a*18, wt0, wt1);
        const float bo = b_out[a];
        float co[4]={bo,bo,bo,bo};
        convP(WA, WB, wt0, wt1, co);
        float ns0[4];
#pragma unroll
        for (int k=0;k<4;++k){ float u=sig_(uo[k]); ns0[k]=hc0[k]+u*(th_(co[k])-hc0[k]); }
        if (SPLIT){
          store_bf4(&wsb[(size_t)a*IMG + gidx], ns0);
        } else {
#pragma unroll
          for (int k=0;k<4;++k)
            acc[k] = fmaf(ns0[k], w_read[(size_t)(gidx+k)*PCNT + a], acc[k]);
        }
      }
    }

    float ra2[4];
    { // strip over I1: reset_{a+1} (+ low plant a+1 gates)
      float WA[3][6], WB[3][6], wt0[9], wt1[9];
      loadW(sm[1], trow+1, gC, WA, WB);
      load_w18(w_reset + (a+1)*18, wt0, wt1);
      const float br = b_reset[a+1];
      ra2[0]=br; ra2[1]=br; ra2[2]=br; ra2[3]=br;
      convP(WA, WB, wt0, wt1, ra2);
      if (low){
        load_w18(w_update + (a+1)*18, wt0, wt1);
        const float bu = b_update[a+1];
        float uo[4]={bu,bu,bu,bu};
        convP(WA, WB, wt0, wt1, uo);
        load_w18(w_out + (a+1)*18, wt0, wt1);
        const float bo = b_out[a+1];
        float co[4]={bo,bo,bo,bo};
        convP(WA, WB, wt0, wt1, co);
        float ns1[4];
#pragma unroll
        for (int k=0;k<4;++k){ float u=sig_(uo[k]); ns1[k]=hc1[k]+u*(th_(co[k])-hc1[k]); }
        if (SPLIT){
          store_bf4(&wsb[(size_t)(a+1)*IMG + gidx], ns1);
        } else {
#pragma unroll
          for (int k=0;k<4;++k)
            acc[k] = fmaf(ns1[k], w_read[(size_t)(gidx+k)*PCNT + (a+1)], acc[k]);
        }
      }
    }

    // edge reset sigact inputs (hr halo px not covered by interior strips)
    float rsA[4], rsB[4];
    if (eAct){
      float wt0[9], wt1[9];
      if (estrip){
        float EA[3][6], EB[3][6];
        const int eg = ec0 >> 1;
        loadW(sm[0], erow-1, eg, EA, EB);
        load_w18(w_reset + a*18, wt0, wt1);
        const float br = b_reset[a];
        rsA[0]=br; rsA[1]=br; rsA[2]=br; rsA[3]=br;
        convP(EA, EB, wt0, wt1, rsA);
        loadW(sm[1], erow-1, eg, EA, EB);
        load_w18(w_reset + (a+1)*18, wt0, wt1);
        const float br1 = b_reset[a+1];
        rsB[0]=br1; rsB[1]=br1; rsB[2]=br1; rsB[3]=br1;
        convP(EA, EB, wt0, wt1, rsB);
      } else {
        float SA[3][4], SB[3][4];
        const int eg = ec0 >> 1, odd = ec0 & 1;
        loadS(sm[0], erow-1, eg, SA, SB);
        load_w18(w_reset + a*18, wt0, wt1);
        rsA[0] = convS(SA, SB, wt0, wt1, b_reset[a], odd);
        loadS(sm[1], erow-1, eg, SA, SB);
        load_w18(w_reset + (a+1)*18, wt0, wt1);
        rsB[0] = convS(SA, SB, wt0, wt1, b_reset[a+1], odd);
      }
    }
    __syncthreads();   // all reads of I0/I1 source data done

    // hr write: hr_a -> I0 A-slots, hr_{a+1} -> I0 B-slots (rows 1..34, cols 3..36)
    {
      float* d = &sm[0][(trow+2)*PITCH_I + 2*(tcol+4)];
      d[1] = hc0[0]*sig_(ra[0]);
      *(float2*)(d+4) = make_float2(hc0[1]*sig_(ra[1]), hc0[2]*sig_(ra[2]));
      d[8] = hc0[3]*sig_(ra[3]);
      d[3] = hc1[0]*sig_(ra2[0]);
      *(float2*)(d+6) = make_float2(hc1[1]*sig_(ra2[1]), hc1[2]*sig_(ra2[2]));
      d[10]= hc1[3]*sig_(ra2[3]);
    }
    if (eAct){
      if (estrip){
        const float* s2 = &sm[2][erow*PITCH_I + 2*ec0];
        float* d = &sm[0][erow*PITCH_I + 2*ec0];
        d[1]  = s2[1] *sig_(rsA[0]);
        d[4]  = s2[4] *sig_(rsA[1]);
        d[5]  = s2[5] *sig_(rsA[2]);
        d[8]  = s2[8] *sig_(rsA[3]);
        d[3]  = s2[3] *sig_(rsB[0]);
        d[6]  = s2[6] *sig_(rsB[1]);
        d[7]  = s2[7] *sig_(rsB[2]);
        d[10] = s2[10]*sig_(rsB[3]);
      } else {
        const int fA = (ec0 & 1) ? 2*ec0+2 : 2*ec0+1;
        const int o  = erow*PITCH_I + fA;
        sm[0][o]   = sm[2][o]  *sig_(rsA[0]);
        sm[0][o+2] = sm[2][o+2]*sig_(rsB[0]);
      }
    }
    __syncthreads();

    { // cand conv over I0 (hr pair) + blend for high plant ph
      float WA[3][6], WB[3][6], wt0[9], wt1[9];
      loadW(sm[0], trow+1, gC, WA, WB);
      load_w18(w_out + ph*18, wt0, wt1);
      const float bo = b_out[ph];
      float cc[4]={bo,bo,bo,bo};
      convP(WA, WB, wt0, wt1, cc);
      const float4 hp4 = *(const float4*)&h[(size_t)ph*IMG + gidx];
      const float hp[4] = {hp4.x,hp4.y,hp4.z,hp4.w};
      float nsH[4];
#pragma unroll
      for (int k=0;k<4;++k){
        float u = sig_(upd[k]);
        nsH[k] = hp[k] + u*(th_(cc[k])-hp[k]);
      }
      if (SPLIT){
        store_bf4(&wsb[(size_t)ph*IMG + gidx], nsH);
      } else {
#pragma unroll
        for (int k=0;k<4;++k)
          acc[k] = fmaf(nsH[k], w_read[(size_t)(gidx+k)*PCNT + ph], acc[k]);
      }
    }
  }

  if (!SPLIT){
#pragma unroll
    for (int k=0;k<4;++k) atomicAdd(&out[gidx+k], acc[k]);
  }
}

extern "C" void kernel_launch(void* const* d_in, const int* in_sizes, int n_in,
                              void* d_out, int out_size, void* d_ws, size_t ws_size,
                              hipStream_t stream) {
  const float* x     = (const float*)d_in[0];
  const float* h     = (const float*)d_in[1];
  const float* wrst  = (const float*)d_in[2];
  const float* brst  = (const float*)d_in[3];
  const float* wupd  = (const float*)d_in[4];
  const float* bupd  = (const float*)d_in[5];
  const float* wout  = (const float*)d_in[6];
  const float* bout  = (const float*)d_in[7];
  const float* wread = (const float*)d_in[8];
  const float* bias  = (const float*)d_in[9];
  float* out = (float*)d_out;
  unsigned short* wsb = (unsigned short*)d_ws;

  const bool split = ws_size >= (size_t)PCNT * IMG * sizeof(unsigned short);
  if (split){
    hipLaunchKernelGGL(gru_fused<true>, dim3(64*16), dim3(NTHREADS), 0, stream,
                       x, h, wrst, brst, wupd, bupd, wout, bout, wread, wsb, out);
    hipLaunchKernelGGL(reduce_out, dim3(IMG/(NTHREADS_R*2)), dim3(NTHREADS_R), 0, stream,
                       wsb, wread, bias, out);
  } else {
    hipLaunchKernelGGL(init_out, dim3(IMG/NTHREADS), dim3(NTHREADS), 0, stream, bias, out);
    hipLaunchKernelGGL(gru_fused<false>, dim3(64*16), dim3(NTHREADS), 0, stream,
                       x, h, wrst, brst, wupd, bupd, wout, bout, wread, wsb, out);
  }
}

// Round 12
// 64.041 us; speedup vs baseline: 1.9879x; 1.9879x over previous
//
#include <hip/hip_runtime.h>

#define PCNT 128
#define RCdim 256
#define IMG (RCdim*RCdim)
#define PITCH 42        // mod 4 = 2 -> rows alternate bank class (conflict fix, R5)
#define TROWS 36        // 32 + 2*ext2
#define TELEMS (TROWS*PITCH)   // 1512 floats
#define NSLOT 360              // float4 load slots per plane (10 per row)
#define NTHREADS 256
#define NTHREADS_R 128
#define NTASK6 (34*6)          // hr strip tasks, 6-wide (204 <= 256: single round)

__device__ __forceinline__ float sig_(float x){ return 1.0f/(1.0f+__expf(-x)); }
__device__ __forceinline__ float th_(float x){ float e=__expf(2.0f*x); return 1.0f-2.0f/(e+1.0f); }

// fp32 -> bf16 round-to-nearest-even
__device__ __forceinline__ unsigned short f2bf(float f){
  unsigned u = __float_as_uint(f);
  u = (u + 0x7fffu + ((u >> 16) & 1u)) >> 16;
  return (unsigned short)u;
}

__device__ __forceinline__ void store_bf4(unsigned short* __restrict__ dst, const float v[4]){
  uint2 p;
  p.x = (unsigned)f2bf(v[0]) | ((unsigned)f2bf(v[1]) << 16);
  p.y = (unsigned)f2bf(v[2]) | ((unsigned)f2bf(v[3]) << 16);
  *(uint2*)dst = p;
}

// Stage one 36x40 plane tile (pitch 42), origin (R0-2, C0-4), zero-padded OOB.
__device__ __forceinline__ void stage4(const float* __restrict__ src, float* __restrict__ dst,
                                       int R0, int C0, int tid){
#pragma unroll
  for (int j=0;j<2;++j){
    int s = j*NTHREADS + tid;
    if (s < NSLOT){
      int rr = s/10, q = s - rr*10;
      int gr = R0-2+rr, gc = C0-4+4*q;
      float4 v = make_float4(0.f,0.f,0.f,0.f);
      if ((unsigned)gr < 256u && (unsigned)gc < 253u)
        v = *(const float4*)(src + gr*RCdim + gc);
      float* d = dst + rr*PITCH + 4*q;
      *(float2*)(d  ) = make_float2(v.x, v.y);
      *(float2*)(d+2) = make_float2(v.z, v.w);
    }
  }
}

// 8-col window via 4x ds_read_b64 (col0 even), rows row0..row0+2
__device__ __forceinline__ void load8(const float* __restrict__ T, int row0, int col0, float v[3][8]){
#pragma unroll
  for (int dy=0;dy<3;++dy){
    const float2* p = (const float2*)&T[(row0+dy)*PITCH + col0];
    float2 a=p[0],b=p[1],c=p[2],d=p[3];
    v[dy][0]=a.x; v[dy][1]=a.y; v[dy][2]=b.x; v[dy][3]=b.y;
    v[dy][4]=c.x; v[dy][5]=c.y; v[dy][6]=d.x; v[dy][7]=d.y;
  }
}

// 3x3 cross-correlation, 1x4 strip; pixel k center col = window_base + OFF+1+k
template<int OFF>
__device__ __forceinline__ void conv_acc(const float v[3][8], const float w9[9], float o[4]){
#pragma unroll
  for (int ky=0; ky<3; ++ky)
#pragma unroll
    for (int kx=0; kx<3; ++kx){
      const float w = w9[ky*3+kx];
#pragma unroll
      for (int k=0;k<4;++k) o[k] = fmaf(w, v[ky][k+kx+OFF], o[k]);
    }
}

// 6 centers from one 8-wide window: center k at window col k+1
__device__ __forceinline__ void conv_acc6(const float v[3][8], const float w9[9], float o[6]){
#pragma unroll
  for (int ky=0; ky<3; ++ky)
#pragma unroll
    for (int kx=0; kx<3; ++kx){
      const float w = w9[ky*3+kx];
#pragma unroll
      for (int k=0;k<6;++k) o[k] = fmaf(w, v[ky][k+kx], o[k]);
    }
}

__device__ __forceinline__ void load_w18(const float* __restrict__ g, float w0[9], float w1[9]){
#pragma unroll
  for (int i=0;i<9;++i){ w0[i]=g[i]; w1[i]=g[9+i]; }
}

// Reset-gate sigmoids for pair (a, a+1): 6-wide strips, 204 tasks, single round.
// Task sIdx: row = sIdx/6 (hr row rr=row+1), s = sIdx%6, window col0 = 2+6s (even).
// Centers cc = col0+1+k = 3+6s+k, k in [0,6); valid cc <= 36 -> k < (s==5 ? 4 : 6).
__device__ __forceinline__ void hr_compute6(float (*sm)[TELEMS],
    const float* __restrict__ w_reset, const float* __restrict__ b_reset,
    int a, int tid, float ga[6], float gb[6]){
  if (tid < NTASK6){
    int row = tid/6, s = tid - row*6;
    int rr = row + 1, col0 = 2 + 6*s;
    float wr0[9],wr1[9];
    load_w18(w_reset + a*18, wr0, wr1);
    const float bra = b_reset[a];
    float va[3][8], vb[3][8];
    load8(sm[0], rr-1, col0, va);
    load8(sm[1], rr-1, col0, vb);
    float ra[6] = {bra,bra,bra,bra,bra,bra};
    conv_acc6(va, wr0, ra); conv_acc6(vb, wr1, ra);
    load8(sm[2], rr-1, col0, va);
    load8(sm[3], rr-1, col0, vb);
    load_w18(w_reset + (a+1)*18, wr0, wr1);
    const float brb = b_reset[a+1];
    float rb[6] = {brb,brb,brb,brb,brb,brb};
    conv_acc6(va, wr0, rb); conv_acc6(vb, wr1, rb);
#pragma unroll
    for (int k=0;k<6;++k){ ga[k]=sig_(ra[k]); gb[k]=sig_(rb[k]); }
  }
}

// hr_a -> sm[0] interior, hr_{a+1} -> sm[2] interior (rows 1..34, cols 3..36).
__device__ __forceinline__ void hr_write6(float (*sm)[TELEMS], int tid,
    const float ga[6], const float gb[6]){
  if (tid < NTASK6){
    int row = tid/6, s = tid - row*6;
    int rr = row + 1, col0 = 2 + 6*s;
    const int kn = (s==5) ? 4 : 6;
#pragma unroll
    for (int k=0;k<6;++k){
      if (k < kn){
        int o = rr*PITCH + col0 + 1 + k;
        sm[0][o] = sm[4][o] * ga[k];
        sm[2][o] = sm[5][o] * gb[k];
      }
    }
  }
}

__global__ void init_out(const float* __restrict__ bias, float* __restrict__ out){
  int i = blockIdx.x * NTHREADS + threadIdx.x;
  out[i] = bias[i];
}

// out[px] = bias[px] + sum_p ns[p][px] * w_read[px][p]; ns is bf16, 2 px per thread
__global__ void __launch_bounds__(NTHREADS_R)
reduce_out(const unsigned short* __restrict__ ns, const float* __restrict__ w_read,
           const float* __restrict__ bias, float* __restrict__ out){
  const int px0 = (blockIdx.x*NTHREADS_R + threadIdx.x)*2;
  float acc0 = bias[px0], acc1 = bias[px0+1];
  const float* wr0 = w_read + (size_t)px0*PCNT;
  const float* wr1 = wr0 + PCNT;
#pragma unroll 4
  for (int p0 = 0; p0 < PCNT; p0 += 4){
    const float4 wa = *(const float4*)&wr0[p0];
    const float4 wb = *(const float4*)&wr1[p0];
#pragma unroll
    for (int j=0;j<4;++j){
      unsigned v = *(const unsigned*)&ns[(size_t)(p0+j)*IMG + px0];
      float n0 = __uint_as_float(v << 16);
      float n1 = __uint_as_float(v & 0xffff0000u);
      acc0 = fmaf(n0, (&wa.x)[j], acc0);
      acc1 = fmaf(n1, (&wb.x)[j], acc1);
    }
  }
  out[px0]   = acc0;
  out[px0+1] = acc1;
}

// R10 structure exactly (spill-free at launch_bounds(256,4)); hr phase re-tiled to
// 6-wide strips (204 tasks, single balanced round; was 306 tasks/2 rounds).
template<bool SPLIT>
__global__ void __launch_bounds__(NTHREADS, 4)
gru_fused(const float* __restrict__ x, const float* __restrict__ h,
          const float* __restrict__ w_reset, const float* __restrict__ b_reset,
          const float* __restrict__ w_update, const float* __restrict__ b_update,
          const float* __restrict__ w_out, const float* __restrict__ b_out,
          const float* __restrict__ w_read, unsigned short* __restrict__ wsb,
          float* __restrict__ out)
{
  __shared__ float sm[6][TELEMS];  // 36288 B -> 4 blocks/CU
  const int tid  = threadIdx.x;
  const int bid  = blockIdx.x;
  const int pg   = bid & 15;
  const int tile = bid >> 4;
  const int R0 = (tile >> 3) * 32;
  const int C0 = (tile & 7) * 32;
  const int trow = tid >> 3;
  const int tcol = (tid & 7) * 4;
  const int gidx = (R0 + trow) * RCdim + C0 + tcol;

  float acc[4] = {0.f,0.f,0.f,0.f};
  float v0[3][8], v1[3][8];

  // ==== Phase A: a = 4pg+2t -> low a, low a+1, high 64+2pg+t ====
#pragma unroll 1
  for (int t = 0; t < 2; ++t){
    const int a  = 4*pg + 2*t;
    const int ph = 64 + 2*pg + t;
    __syncthreads();
    stage4(x + (size_t)(2*a  )*IMG, sm[0], R0,C0,tid);
    stage4(x + (size_t)(2*a+1)*IMG, sm[1], R0,C0,tid);
    stage4(x + (size_t)(2*a+2)*IMG, sm[2], R0,C0,tid);
    stage4(x + (size_t)(2*a+3)*IMG, sm[3], R0,C0,tid);
    stage4(h + (size_t)(a    )*IMG, sm[4], R0,C0,tid);
    stage4(h + (size_t)(a+1  )*IMG, sm[5], R0,C0,tid);
    __syncthreads();

    float hc0[4], hc1[4], uH[4];
    { // high update conv (h_a, h_{a+1}); capture h centers for lows
      float wa[9], wb[9];
      load_w18(w_update + ph*18, wa, wb);
      const float b = b_update[ph];
      float uo[4] = {b,b,b,b};
      load8(sm[4], trow+1, tcol+2, v0);
      load8(sm[5], trow+1, tcol+2, v1);
      conv_acc<1>(v0, wa, uo); conv_acc<1>(v1, wb, uo);
#pragma unroll
      for (int k=0;k<4;++k){ hc0[k]=v0[1][k+2]; hc1[k]=v1[1][k+2]; uH[k]=sig_(uo[k]); }
    }
    { // low plant a
      float wua[9],wub[9],woa[9],wob[9];
      load_w18(w_update + a*18, wua, wub);
      load_w18(w_out    + a*18, woa, wob);
      const float bu=b_update[a], bo=b_out[a];
      float uo[4]={bu,bu,bu,bu}, co[4]={bo,bo,bo,bo};
      load8(sm[0], trow+1, tcol+2, v0);
      load8(sm[1], trow+1, tcol+2, v1);
      conv_acc<1>(v0, wua, uo); conv_acc<1>(v1, wub, uo);
      conv_acc<1>(v0, woa, co); conv_acc<1>(v1, wob, co);
      float ns0[4];
#pragma unroll
      for (int k=0;k<4;++k){ float u=sig_(uo[k]); ns0[k]=hc0[k]+u*(th_(co[k])-hc0[k]); }
      if (SPLIT){
        store_bf4(&wsb[(size_t)a*IMG + gidx], ns0);
      } else {
#pragma unroll
        for (int k=0;k<4;++k)
          acc[k] = fmaf(ns0[k], w_read[(size_t)(gidx+k)*PCNT + a], acc[k]);
      }
    }
    { // low plant a+1
      float wua[9],wub[9],woa[9],wob[9];
      load_w18(w_update + (a+1)*18, wua, wub);
      load_w18(w_out    + (a+1)*18, woa, wob);
      const float bu=b_update[a+1], bo=b_out[a+1];
      float uo[4]={bu,bu,bu,bu}, co[4]={bo,bo,bo,bo};
      load8(sm[2], trow+1, tcol+2, v0);
      load8(sm[3], trow+1, tcol+2, v1);
      conv_acc<1>(v0, wua, uo); conv_acc<1>(v1, wub, uo);
      conv_acc<1>(v0, woa, co); conv_acc<1>(v1, wob, co);
      float ns1[4];
#pragma unroll
      for (int k=0;k<4;++k){ float u=sig_(uo[k]); ns1[k]=hc1[k]+u*(th_(co[k])-hc1[k]); }
      if (SPLIT){
        store_bf4(&wsb[(size_t)(a+1)*IMG + gidx], ns1);
      } else {
#pragma unroll
        for (int k=0;k<4;++k)
          acc[k] = fmaf(ns1[k], w_read[(size_t)(gidx+k)*PCNT + (a+1)], acc[k]);
      }
    }
    float ga[6], gb[6];
    hr_compute6(sm, w_reset, b_reset, a, tid, ga, gb);
    __syncthreads();
    hr_write6(sm, tid, ga, gb);
    __syncthreads();
    { // high cand conv (hr pair) + blend
      float woa[9], wob[9];
      load_w18(w_out + ph*18, woa, wob);
      const float bo = b_out[ph];
      float co[4]={bo,bo,bo,bo};
      load8(sm[0], trow+1, tcol+2, v0);
      load8(sm[2], trow+1, tcol+2, v1);
      conv_acc<1>(v0, woa, co); conv_acc<1>(v1, wob, co);
      const float4 hp4 = *(const float4*)&h[(size_t)ph*IMG + gidx];
      const float hp[4] = {hp4.x,hp4.y,hp4.z,hp4.w};
      float nsH[4];
#pragma unroll
      for (int k=0;k<4;++k) nsH[k] = hp[k] + uH[k]*(th_(co[k])-hp[k]);
      if (SPLIT){
        store_bf4(&wsb[(size_t)ph*IMG + gidx], nsH);
      } else {
#pragma unroll
        for (int k=0;k<4;++k)
          acc[k] = fmaf(nsH[k], w_read[(size_t)(gidx+k)*PCNT + ph], acc[k]);
      }
    }
  }

  // ==== Phase B: a = 64+4pg+2t -> high plant 96+2pg+t ====
#pragma unroll 1
  for (int t = 0; t < 2; ++t){
    const int a    = 64 + 4*pg + 2*t;
    const int ph   = 96 + 2*pg + t;
    const int base = 8*pg + 4*t;
    __syncthreads();
    stage4(h + (size_t)(base  )*IMG, sm[0], R0,C0,tid);
    stage4(h + (size_t)(base+1)*IMG, sm[1], R0,C0,tid);
    stage4(h + (size_t)(base+2)*IMG, sm[2], R0,C0,tid);
    stage4(h + (size_t)(base+3)*IMG, sm[3], R0,C0,tid);
    stage4(h + (size_t)(a     )*IMG, sm[4], R0,C0,tid);
    stage4(h + (size_t)(a+1   )*IMG, sm[5], R0,C0,tid);
    __syncthreads();

    float uH[4];
    {
      float wa[9], wb[9];
      load_w18(w_update + ph*18, wa, wb);
      const float bu = b_update[ph];
      float uo[4] = {bu,bu,bu,bu};
      load8(sm[4], trow+1, tcol+2, v0);
      load8(sm[5], trow+1, tcol+2, v1);
      conv_acc<1>(v0, wa, uo); conv_acc<1>(v1, wb, uo);
#pragma unroll
      for (int k=0;k<4;++k) uH[k]=sig_(uo[k]);
    }
    float ga[6], gb[6];
    hr_compute6(sm, w_reset, b_reset, a, tid, ga, gb);
    __syncthreads();
    hr_write6(sm, tid, ga, gb);
    __syncthreads();
    {
      float wa[9], wb[9];
      load_w18(w_out + ph*18, wa, wb);
      const float bo = b_out[ph];
      float co[4] = {bo,bo,bo,bo};
      load8(sm[0], trow+1, tcol+2, v0);
      load8(sm[2], trow+1, tcol+2, v1);
      conv_acc<1>(v0, wa, co); conv_acc<1>(v1, wb, co);
      const float4 hp4 = *(const float4*)&h[(size_t)ph*IMG + gidx];
      const float hp[4] = {hp4.x,hp4.y,hp4.z,hp4.w};
      float nsH[4];
#pragma unroll
      for (int k=0;k<4;++k) nsH[k] = hp[k] + uH[k]*(th_(co[k])-hp[k]);
      if (SPLIT){
        store_bf4(&wsb[(size_t)ph*IMG + gidx], nsH);
      } else {
#pragma unroll
        for (int k=0;k<4;++k)
          acc[k] = fmaf(nsH[k], w_read[(size_t)(gidx+k)*PCNT + ph], acc[k]);
      }
    }
  }

  if (!SPLIT){
#pragma unroll
    for (int k=0;k<4;++k) atomicAdd(&out[gidx+k], acc[k]);
  }
}

extern "C" void kernel_launch(void* const* d_in, const int* in_sizes, int n_in,
                              void* d_out, int out_size, void* d_ws, size_t ws_size,
                              hipStream_t stream) {
  const float* x     = (const float*)d_in[0];
  const float* h     = (const float*)d_in[1];
  const float* wrst  = (const float*)d_in[2];
  const float* brst  = (const float*)d_in[3];
  const float* wupd  = (const float*)d_in[4];
  const float* bupd  = (const float*)d_in[5];
  const float* wout  = (const float*)d_in[6];
  const float* bout  = (const float*)d_in[7];
  const float* wread = (const float*)d_in[8];
  const float* bias  = (const float*)d_in[9];
  float* out = (float*)d_out;
  unsigned short* wsb = (unsigned short*)d_ws;

  const bool split = ws_size >= (size_t)PCNT * IMG * sizeof(unsigned short);
  if (split){
    hipLaunchKernelGGL(gru_fused<true>, dim3(64*16), dim3(NTHREADS), 0, stream,
                       x, h, wrst, brst, wupd, bupd, wout, bout, wread, wsb, out);
    hipLaunchKernelGGL(reduce_out, dim3(IMG/(NTHREADS_R*2)), dim3(NTHREADS_R), 0, stream,
                       wsb, wread, bias, out);
  } else {
    hipLaunchKernelGGL(init_out, dim3(IMG/NTHREADS), dim3(NTHREADS), 0, stream, bias, out);
    hipLaunchKernelGGL(gru_fused<false>, dim3(64*16), dim3(NTHREADS), 0, stream,
                       x, h, wrst, brst, wupd, bupd, wout, bout, wread, wsb, out);
  }
}